// Round 1
// baseline (32289.078 us; speedup 1.0000x reference)
//
#include <hip/hip_runtime.h>
#include <math.h>

// Problem constants
#define BB 16      // batch
#define TT 16      // time (input)
#define EE 128     // embed
#define KS 15      // kernel
#define MM 41      // map size
#define OO 4       // orientations
#define VR 7       // view range
#define SS 27      // localize output spatial (41 - 2*7)
#define NSTEP 15
#define PP (MM*MM)          // 1681
#define NROWS (BB*PP)       // 26896

#define RAWS_OFF 0
#define SPS_OFF  1613760            // 16*15*4*1681
#define MAPS_OFF 3227520            // 2*SPS

__device__ __forceinline__ float sigf(float x) { return 1.f / (1.f + expf(-x)); }

// rotate kernel coords (r,c) by o*90deg CCW -> source (ir,ic) in 15x15 image
__device__ __forceinline__ int rotoff(int o, int r, int c) {
    int ir, ic;
    if (o == 0)      { ir = r;      ic = c;      }
    else if (o == 1) { ir = c;      ic = 14 - r; }
    else if (o == 2) { ir = 14 - r; ic = 14 - c; }
    else             { ir = 14 - c; ic = r;      }
    return ir * 15 + ic;
}

// ---------------- pose init: zeros + one-hot at (o=0, 20,20) ----------------
__global__ void k_init(float* __restrict__ pose) {
    int idx = blockIdx.x * 256 + threadIdx.x;
    if (idx < BB * OO * MM * MM) {
        int r = idx % (OO * MM * MM);
        pose[idx] = (r == (20 * MM + 20)) ? 1.f : 0.f;
    }
}

// ---------------- weight prep: Wc[k][jp], jp = jj*4+g, j = g*128+jj ----------
__global__ void k_prep(const float* __restrict__ wih, const float* __restrict__ whh,
                       const float* __restrict__ bih, const float* __restrict__ bhh,
                       float* __restrict__ Wc, float* __restrict__ bc) {
    int idx = blockIdx.x * 256 + threadIdx.x;   // [0, 256*512)
    int k = idx >> 9, jp = idx & 511;
    int jj = jp >> 2, g = jp & 3, j = g * 128 + jj;
    Wc[idx] = (k < 128) ? wih[j * 128 + k] : whh[j * 128 + (k - 128)];
    if (idx < 512) {
        int jj2 = idx >> 2, g2 = idx & 3, j2 = g2 * 128 + jj2;
        bc[idx] = bih[j2] + bhh[j2];
    }
}

// ---------------- register: conv-transpose of pose with rotated images -------
// reg[b, p=(y,x), e] = sum_{o,dy,dx} pose[b,o,y+7-dy,x+7-dx] * rot_o(img[b,t])[e,dy,dx]
__global__ __launch_bounds__(256) void k_register(const float* __restrict__ images,
                                                  const float* __restrict__ pose,
                                                  float* __restrict__ reg, int t) {
    __shared__ float ps[OO * MM * MM];   // 6724 floats
    __shared__ float wsm[OO * KS * KS];  // 900 floats
    const int b = blockIdx.x >> 7;
    const int e = blockIdx.x & 127;
    const int tid = threadIdx.x;

    for (int i = tid; i < OO * MM * MM; i += 256) ps[i] = pose[(size_t)b * OO * MM * MM + i];
    const float* img = images + ((size_t)(b * TT + t) * EE + e) * (KS * KS);
    for (int i = tid; i < OO * KS * KS; i += 256) {
        int o = i / 225, rc = i % 225, r = rc / 15, c = rc % 15;
        wsm[i] = img[rotoff(o, r, c)];
    }
    __syncthreads();

    for (int p = tid; p < PP; p += 256) {
        int y = p / MM, x = p - y * MM;
        int dylo = (y - 33 > 0) ? y - 33 : 0;
        int dyhi = (y + 7 < 14) ? y + 7 : 14;
        int dxlo = (x - 33 > 0) ? x - 33 : 0;
        int dxhi = (x + 7 < 14) ? x + 7 : 14;
        float acc = 0.f;
        #pragma unroll
        for (int o = 0; o < OO; ++o) {
            for (int dy = dylo; dy <= dyhi; ++dy) {
                const float* pr = &ps[(o * MM + (y + VR - dy)) * MM + (x + VR)];
                const float* wr = &wsm[(o * KS + dy) * KS];
                float s = 0.f;
                for (int dx = dxlo; dx <= dxhi; ++dx) s += pr[-dx] * wr[dx];
                acc += s;
            }
        }
        reg[((size_t)b * PP + p) * EE + e] = acc;
    }
}

// ---------------- LSTM: gates GEMM [NROWS x 256]@[256 x 512] + epilogue ------
__global__ __launch_bounds__(256) void k_lstm(const float* __restrict__ regb,
                                              const float* __restrict__ hin,
                                              const float* __restrict__ Wc,
                                              const float* __restrict__ bc,
                                              float* __restrict__ hout,
                                              float* __restrict__ cst) {
    __shared__ float As[64][17];
    __shared__ __align__(16) float Wsm[16][64];
    const int tid = threadIdx.x;
    const int tx = tid & 15;     // col group (jj)
    const int ty = tid >> 4;     // row group
    const int n0 = blockIdx.x * 64;
    const int jp0 = blockIdx.y * 64;

    const int a_nl = tid >> 2;
    const int a_kl = (tid & 3) * 4;
    const int w_kl = tid >> 4;
    const int w_jl = (tid & 15) * 4;

    float acc[4][4] = {{0.f}};

    for (int kt = 0; kt < 16; ++kt) {
        const float* src = (kt < 8) ? regb : hin;
        const int koff = (kt < 8) ? kt * 16 : (kt - 8) * 16;
        int n = n0 + a_nl;
        float4 av = make_float4(0.f, 0.f, 0.f, 0.f);
        if (n < NROWS) av = *(const float4*)(src + (size_t)n * EE + koff + a_kl);
        As[a_nl][a_kl + 0] = av.x; As[a_nl][a_kl + 1] = av.y;
        As[a_nl][a_kl + 2] = av.z; As[a_nl][a_kl + 3] = av.w;
        float4 wv = *(const float4*)(Wc + (size_t)(kt * 16 + w_kl) * 512 + jp0 + w_jl);
        *(float4*)&Wsm[w_kl][w_jl] = wv;
        __syncthreads();
        #pragma unroll
        for (int kl = 0; kl < 16; ++kl) {
            float a0 = As[ty * 4 + 0][kl];
            float a1 = As[ty * 4 + 1][kl];
            float a2 = As[ty * 4 + 2][kl];
            float a3 = As[ty * 4 + 3][kl];
            float4 bv = *(const float4*)&Wsm[kl][tx * 4];
            acc[0][0] += a0 * bv.x; acc[0][1] += a0 * bv.y; acc[0][2] += a0 * bv.z; acc[0][3] += a0 * bv.w;
            acc[1][0] += a1 * bv.x; acc[1][1] += a1 * bv.y; acc[1][2] += a1 * bv.z; acc[1][3] += a1 * bv.w;
            acc[2][0] += a2 * bv.x; acc[2][1] += a2 * bv.y; acc[2][2] += a2 * bv.z; acc[2][3] += a2 * bv.w;
            acc[3][0] += a3 * bv.x; acc[3][1] += a3 * bv.y; acc[3][2] += a3 * bv.z; acc[3][3] += a3 * bv.w;
        }
        __syncthreads();
    }

    const int jj = (jp0 >> 2) + tx;
    float4 bv = *(const float4*)(bc + jj * 4);
    #pragma unroll
    for (int i = 0; i < 4; ++i) {
        int n = n0 + ty * 4 + i;
        if (n >= NROWS) continue;
        float gi = acc[i][0] + bv.x;
        float gf = acc[i][1] + bv.y;
        float gg = acc[i][2] + bv.z;
        float go = acc[i][3] + bv.w;
        size_t off = (size_t)n * EE + jj;
        float cv = cst[off];
        float c2 = sigf(gf) * cv + sigf(gi) * tanhf(gg);
        float h2 = sigf(go) * tanhf(c2);
        cst[off] = c2;
        hout[off] = h2;
    }
}

// ---------------- maps: transpose h[(b,p),e] -> out[b,t,e,p] -----------------
__global__ __launch_bounds__(256) void k_maps(const float* __restrict__ h,
                                              float* __restrict__ out, int t) {
    __shared__ float tile[32][33];
    const int b = blockIdx.z;
    const int p0 = blockIdx.x * 32;
    const int e0 = blockIdx.y * 32;
    const int tx = threadIdx.x & 31;
    const int ty0 = threadIdx.x >> 5;
    for (int ty = ty0; ty < 32; ty += 8) {
        int p = p0 + ty;
        tile[ty][tx] = (p < PP) ? h[((size_t)b * PP + p) * EE + e0 + tx] : 0.f;
    }
    __syncthreads();
    size_t base = MAPS_OFF + ((size_t)(b * NSTEP + t) * EE) * PP;
    for (int ty = ty0; ty < 32; ty += 8) {
        int e = e0 + ty;
        int p = p0 + tx;
        if (p < PP) out[base + (size_t)e * PP + p] = tile[tx][ty];
    }
}

// ---------------- localize: raw[b,o,y,x] = sum_{e,dy,dx} m*w -----------------
__global__ __launch_bounds__(256) void k_localize(const float* __restrict__ h,
                                                  const float* __restrict__ images,
                                                  float* __restrict__ raw, int t) {
    const int y = blockIdx.x;   // 0..26
    const int o = blockIdx.y;   // 0..3
    const int b = blockIdx.z;   // 0..15
    const int tid = threadIdx.x;
    const int xc = tid >> 3;    // 0..31 (use 0..26)
    const int ec = tid & 7;     // 8 chunks of 16 e

    const float* img = images + ((size_t)(b * TT + t + 1) * EE) * 225;
    float acc = 0.f;
    if (xc < SS) {
        for (int dy = 0; dy < KS; ++dy) {
            for (int dx = 0; dx < KS; ++dx) {
                const int roff = rotoff(o, dy, dx);
                const float* mp = &h[((size_t)b * PP + (y + dy) * MM + (xc + dx)) * EE + ec * 16];
                const float* wp = img + (size_t)(ec * 16) * 225 + roff;
                #pragma unroll
                for (int e4 = 0; e4 < 4; ++e4) {
                    float4 mv = *(const float4*)(mp + e4 * 4);
                    acc += mv.x * wp[(e4 * 4 + 0) * 225];
                    acc += mv.y * wp[(e4 * 4 + 1) * 225];
                    acc += mv.z * wp[(e4 * 4 + 2) * 225];
                    acc += mv.w * wp[(e4 * 4 + 3) * 225];
                }
            }
        }
    }
    __shared__ float partial[32][8];
    partial[xc][ec] = acc;
    __syncthreads();
    if (tid < SS) {
        float s = 0.f;
        #pragma unroll
        for (int q = 0; q < 8; ++q) s += partial[tid][q];
        raw[(((size_t)b * OO + o) * SS + y) * SS + tid] = s;
    }
}

// ---------------- softmax over (O*27*27) + padded writes + pose update -------
__global__ __launch_bounds__(256) void k_softmax(const float* __restrict__ raw,
                                                 float* __restrict__ out,
                                                 float* __restrict__ pose, int t) {
    const int b = blockIdx.x, tid = threadIdx.x;
    __shared__ float red[256];
    const float* rb = raw + (size_t)b * OO * SS * SS;
    const int NTOT = OO * SS * SS;  // 2916

    float mx = -3.4e38f;
    for (int i = tid; i < NTOT; i += 256) mx = fmaxf(mx, rb[i]);
    red[tid] = mx; __syncthreads();
    for (int s = 128; s > 0; s >>= 1) {
        if (tid < s) red[tid] = fmaxf(red[tid], red[tid + s]);
        __syncthreads();
    }
    mx = red[0]; __syncthreads();

    float sm = 0.f;
    for (int i = tid; i < NTOT; i += 256) sm += expf(rb[i] - mx);
    red[tid] = sm; __syncthreads();
    for (int s = 128; s > 0; s >>= 1) {
        if (tid < s) red[tid] += red[tid + s];
        __syncthreads();
    }
    const float inv = 1.f / red[0];

    float* rawOut = out + RAWS_OFF + ((size_t)(b * NSTEP + t) * OO) * PP;
    float* spOut  = out + SPS_OFF  + ((size_t)(b * NSTEP + t) * OO) * PP;
    float* pb = pose + (size_t)b * OO * MM * MM;
    for (int i = tid; i < OO * MM * MM; i += 256) {
        int o = i / (MM * MM), rem = i % (MM * MM), yy = rem / MM - VR, xx = rem % MM - VR;
        float rv = 0.f, sv = 0.f;
        if ((unsigned)yy < SS && (unsigned)xx < SS) {
            float r = rb[(o * SS + yy) * SS + xx];
            rv = r;
            sv = expf(r - mx) * inv;
        }
        rawOut[i] = rv;
        spOut[i] = sv;
        pb[i] = sv;
    }
}

extern "C" void kernel_launch(void* const* d_in, const int* in_sizes, int n_in,
                              void* d_out, int out_size, void* d_ws, size_t ws_size,
                              hipStream_t stream) {
    const float* images = (const float*)d_in[0];
    const float* wih    = (const float*)d_in[1];
    const float* whh    = (const float*)d_in[2];
    const float* bih    = (const float*)d_in[3];
    const float* bhh    = (const float*)d_in[4];
    float* out = (float*)d_out;
    float* ws  = (float*)d_ws;

    float* pose = ws;                       // 107584
    float* hA   = pose + 107584;            // 3442688
    float* hB   = hA + 3442688;             // 3442688
    float* cst  = hB + 3442688;             // 3442688
    float* regb = cst + 3442688;            // 3442688
    float* raw  = regb + 3442688;           // 46656
    float* Wc   = raw + 46656;              // 131072
    float* bc   = Wc + 131072;              // 512
    // total: 14,056,576 floats = 56.2 MB

    hipMemsetAsync(hA, 0, (size_t)3442688 * 4, stream);
    hipMemsetAsync(cst, 0, (size_t)3442688 * 4, stream);
    k_init<<<421, 256, 0, stream>>>(pose);
    k_prep<<<512, 256, 0, stream>>>(wih, whh, bih, bhh, Wc, bc);

    float* hin = hA;
    float* hout = hB;
    for (int t = 0; t < NSTEP; ++t) {
        k_register<<<BB * EE, 256, 0, stream>>>(images, pose, regb, t);
        k_lstm<<<dim3((NROWS + 63) / 64, 8), 256, 0, stream>>>(regb, hin, Wc, bc, hout, cst);
        k_maps<<<dim3(53, 4, BB), 256, 0, stream>>>(hout, out, t);
        k_localize<<<dim3(SS, OO, BB), 256, 0, stream>>>(hout, images, raw, t);
        k_softmax<<<BB, 256, 0, stream>>>(raw, out, pose, t);
        float* tmp = hin; hin = hout; hout = tmp;
    }
}

// Round 2
// 14304.633 us; speedup vs baseline: 2.2572x; 2.2572x over previous
//
#include <hip/hip_runtime.h>
#include <math.h>

// Problem constants
#define BB 16      // batch
#define TT 16      // time (input)
#define EE 128     // embed
#define KS 15      // kernel
#define MM 41      // map size
#define OO 4       // orientations
#define VR 7       // view range
#define SS 27      // localize output spatial (41 - 2*7)
#define NSTEP 15
#define PP (MM*MM)          // 1681
#define NROWS (BB*PP)       // 26896

#define RAWS_OFF 0
#define SPS_OFF  1613760            // 16*15*4*1681
#define MAPS_OFF 3227520            // 2*SPS

__device__ __forceinline__ float sigf(float x) { return 1.f / (1.f + expf(-x)); }

// rotate kernel coords (r,c) by o*90deg CCW -> source (ir,ic) in 15x15 image
__device__ __forceinline__ int rotoff(int o, int r, int c) {
    int ir, ic;
    if (o == 0)      { ir = r;      ic = c;      }
    else if (o == 1) { ir = c;      ic = 14 - r; }
    else if (o == 2) { ir = 14 - r; ic = 14 - c; }
    else             { ir = 14 - c; ic = r;      }
    return ir * 15 + ic;
}

// ---------------- pose init: zeros + one-hot at (o=0, 20,20) ----------------
__global__ void k_init(float* __restrict__ pose) {
    int idx = blockIdx.x * 256 + threadIdx.x;
    if (idx < BB * OO * MM * MM) {
        int r = idx % (OO * MM * MM);
        pose[idx] = (r == (20 * MM + 20)) ? 1.f : 0.f;
    }
}

// ---------------- weight prep: Wc[k][jp], jp = jj*4+g, j = g*128+jj ----------
__global__ void k_prep(const float* __restrict__ wih, const float* __restrict__ whh,
                       const float* __restrict__ bih, const float* __restrict__ bhh,
                       float* __restrict__ Wc, float* __restrict__ bc) {
    int idx = blockIdx.x * 256 + threadIdx.x;   // [0, 256*512)
    int k = idx >> 9, jp = idx & 511;
    int jj = jp >> 2, g = jp & 3, j = g * 128 + jj;
    Wc[idx] = (k < 128) ? wih[j * 128 + k] : whh[j * 128 + (k - 128)];
    if (idx < 512) {
        int jj2 = idx >> 2, g2 = idx & 3, j2 = g2 * 128 + jj2;
        bc[idx] = bih[j2] + bhh[j2];
    }
}

// ---------------- register: conv-transpose of pose with rotated images -------
// reg[b, p=(y,x), e] = sum_{o,dy,dx} pose[b,o,y+7-dy,x+7-dx] * rot_o(img[b,t])[e,dy,dx]
__global__ __launch_bounds__(256) void k_register(const float* __restrict__ images,
                                                  const float* __restrict__ pose,
                                                  float* __restrict__ reg, int t) {
    __shared__ float ps[OO * MM * MM];   // 6724 floats
    __shared__ float wsm[OO * KS * KS];  // 900 floats
    const int b = blockIdx.x >> 7;
    const int e = blockIdx.x & 127;
    const int tid = threadIdx.x;

    for (int i = tid; i < OO * MM * MM; i += 256) ps[i] = pose[(size_t)b * OO * MM * MM + i];
    const float* img = images + ((size_t)(b * TT + t) * EE + e) * (KS * KS);
    for (int i = tid; i < OO * KS * KS; i += 256) {
        int o = i / 225, rc = i % 225, r = rc / 15, c = rc % 15;
        wsm[i] = img[rotoff(o, r, c)];
    }
    __syncthreads();

    for (int p = tid; p < PP; p += 256) {
        int y = p / MM, x = p - y * MM;
        int dylo = (y - 33 > 0) ? y - 33 : 0;
        int dyhi = (y + 7 < 14) ? y + 7 : 14;
        int dxlo = (x - 33 > 0) ? x - 33 : 0;
        int dxhi = (x + 7 < 14) ? x + 7 : 14;
        float acc = 0.f;
        #pragma unroll
        for (int o = 0; o < OO; ++o) {
            for (int dy = dylo; dy <= dyhi; ++dy) {
                const float* pr = &ps[(o * MM + (y + VR - dy)) * MM + (x + VR)];
                const float* wr = &wsm[(o * KS + dy) * KS];
                float s = 0.f;
                for (int dx = dxlo; dx <= dxhi; ++dx) s += pr[-dx] * wr[dx];
                acc += s;
            }
        }
        reg[((size_t)b * PP + p) * EE + e] = acc;
    }
}

// ---------------- LSTM: gates GEMM [NROWS x 256]@[256 x 512] + epilogue ------
__global__ __launch_bounds__(256) void k_lstm(const float* __restrict__ regb,
                                              const float* __restrict__ hin,
                                              const float* __restrict__ Wc,
                                              const float* __restrict__ bc,
                                              float* __restrict__ hout,
                                              float* __restrict__ cst) {
    __shared__ float As[64][17];
    __shared__ __align__(16) float Wsm[16][64];
    const int tid = threadIdx.x;
    const int tx = tid & 15;     // col group (jj)
    const int ty = tid >> 4;     // row group
    const int n0 = blockIdx.x * 64;
    const int jp0 = blockIdx.y * 64;

    const int a_nl = tid >> 2;
    const int a_kl = (tid & 3) * 4;
    const int w_kl = tid >> 4;
    const int w_jl = (tid & 15) * 4;

    float acc[4][4] = {{0.f}};

    for (int kt = 0; kt < 16; ++kt) {
        const float* src = (kt < 8) ? regb : hin;
        const int koff = (kt < 8) ? kt * 16 : (kt - 8) * 16;
        int n = n0 + a_nl;
        float4 av = make_float4(0.f, 0.f, 0.f, 0.f);
        if (n < NROWS) av = *(const float4*)(src + (size_t)n * EE + koff + a_kl);
        As[a_nl][a_kl + 0] = av.x; As[a_nl][a_kl + 1] = av.y;
        As[a_nl][a_kl + 2] = av.z; As[a_nl][a_kl + 3] = av.w;
        float4 wv = *(const float4*)(Wc + (size_t)(kt * 16 + w_kl) * 512 + jp0 + w_jl);
        *(float4*)&Wsm[w_kl][w_jl] = wv;
        __syncthreads();
        #pragma unroll
        for (int kl = 0; kl < 16; ++kl) {
            float a0 = As[ty * 4 + 0][kl];
            float a1 = As[ty * 4 + 1][kl];
            float a2 = As[ty * 4 + 2][kl];
            float a3 = As[ty * 4 + 3][kl];
            float4 bv = *(const float4*)&Wsm[kl][tx * 4];
            acc[0][0] += a0 * bv.x; acc[0][1] += a0 * bv.y; acc[0][2] += a0 * bv.z; acc[0][3] += a0 * bv.w;
            acc[1][0] += a1 * bv.x; acc[1][1] += a1 * bv.y; acc[1][2] += a1 * bv.z; acc[1][3] += a1 * bv.w;
            acc[2][0] += a2 * bv.x; acc[2][1] += a2 * bv.y; acc[2][2] += a2 * bv.z; acc[2][3] += a2 * bv.w;
            acc[3][0] += a3 * bv.x; acc[3][1] += a3 * bv.y; acc[3][2] += a3 * bv.z; acc[3][3] += a3 * bv.w;
        }
        __syncthreads();
    }

    const int jj = (jp0 >> 2) + tx;
    float4 bv = *(const float4*)(bc + jj * 4);
    #pragma unroll
    for (int i = 0; i < 4; ++i) {
        int n = n0 + ty * 4 + i;
        if (n >= NROWS) continue;
        float gi = acc[i][0] + bv.x;
        float gf = acc[i][1] + bv.y;
        float gg = acc[i][2] + bv.z;
        float go = acc[i][3] + bv.w;
        size_t off = (size_t)n * EE + jj;
        float cv = cst[off];
        float c2 = sigf(gf) * cv + sigf(gi) * tanhf(gg);
        float h2 = sigf(go) * tanhf(c2);
        cst[off] = c2;
        hout[off] = h2;
    }
}

// ---------------- maps: transpose h[(b,p),e] -> out[b,t,e,p] -----------------
__global__ __launch_bounds__(256) void k_maps(const float* __restrict__ h,
                                              float* __restrict__ out, int t) {
    __shared__ float tile[32][33];
    const int b = blockIdx.z;
    const int p0 = blockIdx.x * 32;
    const int e0 = blockIdx.y * 32;
    const int tx = threadIdx.x & 31;
    const int ty0 = threadIdx.x >> 5;
    for (int ty = ty0; ty < 32; ty += 8) {
        int p = p0 + ty;
        tile[ty][tx] = (p < PP) ? h[((size_t)b * PP + p) * EE + e0 + tx] : 0.f;
    }
    __syncthreads();
    size_t base = MAPS_OFF + ((size_t)(b * NSTEP + t) * EE) * PP;
    for (int ty = ty0; ty < 32; ty += 8) {
        int e = e0 + ty;
        int p = p0 + tx;
        if (p < PP) out[base + (size_t)e * PP + p] = tile[tx][ty];
    }
}

// ---------------- localize: raw[b,o,y,x] = sum_{e,dy,dx} m*w -----------------
// Rewritten: LDS-staged rotated weights (e-half per block), register-cached
// weight fragments reused across a 7-row accumulator strip.
// rawp layout: [eh=2][b][o][27][27] partial sums; softmax adds the halves.
__global__ __launch_bounds__(256) void k_localize(const float* __restrict__ h,
                                                  const float* __restrict__ images,
                                                  float* __restrict__ rawp, int t) {
    __shared__ float wsm[225][64];     // 57.6 KB
    const int y0 = blockIdx.x * 7;     // ytile: 0,7,14,21
    const int o  = blockIdx.y;
    const int b  = blockIdx.z >> 1;
    const int eh = blockIdx.z & 1;
    const int tid = threadIdx.x;

    // stage rotated weights: wsm[k][e] = img[e][rotoff(o, k/15, k%15)]
    const float* img = images + ((size_t)(b * TT + t + 1) * EE + eh * 64) * 225;
    for (int i = tid; i < 225 * 64; i += 256) {
        int k = i >> 6, e = i & 63;
        int r = k / 15, c = k - r * 15;
        wsm[k][e] = img[e * 225 + rotoff(o, r, c)];
    }
    __syncthreads();

    const int ec = tid & 7;            // 8 e's per lane group
    const int xc = tid >> 3;           // 0..31, active 0..26
    float acc[7] = {0.f, 0.f, 0.f, 0.f, 0.f, 0.f, 0.f};

    if (xc < SS) {
        const float* hb = h + (size_t)b * PP * EE + eh * 64 + ec * 8;
        int dy = 0, dx = 0;
        for (int k = 0; k < 225; ++k) {
            float4 w0 = *(const float4*)&wsm[k][ec * 8];
            float4 w1 = *(const float4*)&wsm[k][ec * 8 + 4];
            const float* hp = hb + (size_t)((y0 + dy) * MM + xc + dx) * EE;
            #pragma unroll
            for (int yy = 0; yy < 7; ++yy) {
                if (y0 + yy < SS) {
                    float4 h0 = *(const float4*)(hp + yy * (MM * EE));
                    float4 h1 = *(const float4*)(hp + yy * (MM * EE) + 4);
                    acc[yy] += h0.x * w0.x + h0.y * w0.y + h0.z * w0.z + h0.w * w0.w
                             + h1.x * w1.x + h1.y * w1.y + h1.z * w1.z + h1.w * w1.w;
                }
            }
            if (++dx == 15) { dx = 0; ++dy; }
        }
    }

    // reduce across the 8 ec lanes (consecutive lanes within a wave)
    #pragma unroll
    for (int yy = 0; yy < 7; ++yy) {
        float v = acc[yy];
        v += __shfl_xor(v, 1);
        v += __shfl_xor(v, 2);
        v += __shfl_xor(v, 4);
        if (ec == 0 && xc < SS && y0 + yy < SS) {
            rawp[(((size_t)eh * BB + b) * OO + o) * (SS * SS) + (y0 + yy) * SS + xc] = v;
        }
    }
}

// ---------------- softmax over (O*27*27) + padded writes + pose update -------
__global__ __launch_bounds__(256) void k_softmax(const float* __restrict__ rawp,
                                                 float* __restrict__ out,
                                                 float* __restrict__ pose, int t) {
    const int b = blockIdx.x, tid = threadIdx.x;
    __shared__ float red[256];
    const float* r0 = rawp + (size_t)b * (OO * SS * SS);
    const float* r1 = rawp + (size_t)(BB + b) * (OO * SS * SS);
    const int NTOT = OO * SS * SS;  // 2916

    float mx = -3.4e38f;
    for (int i = tid; i < NTOT; i += 256) mx = fmaxf(mx, r0[i] + r1[i]);
    red[tid] = mx; __syncthreads();
    for (int s = 128; s > 0; s >>= 1) {
        if (tid < s) red[tid] = fmaxf(red[tid], red[tid + s]);
        __syncthreads();
    }
    mx = red[0]; __syncthreads();

    float sm = 0.f;
    for (int i = tid; i < NTOT; i += 256) sm += expf(r0[i] + r1[i] - mx);
    red[tid] = sm; __syncthreads();
    for (int s = 128; s > 0; s >>= 1) {
        if (tid < s) red[tid] += red[tid + s];
        __syncthreads();
    }
    const float inv = 1.f / red[0];

    float* rawOut = out + RAWS_OFF + ((size_t)(b * NSTEP + t) * OO) * PP;
    float* spOut  = out + SPS_OFF  + ((size_t)(b * NSTEP + t) * OO) * PP;
    float* pb = pose + (size_t)b * OO * MM * MM;
    for (int i = tid; i < OO * MM * MM; i += 256) {
        int o = i / (MM * MM), rem = i % (MM * MM), yy = rem / MM - VR, xx = rem % MM - VR;
        float rv = 0.f, sv = 0.f;
        if ((unsigned)yy < SS && (unsigned)xx < SS) {
            int idx = (o * SS + yy) * SS + xx;
            float r = r0[idx] + r1[idx];
            rv = r;
            sv = expf(r - mx) * inv;
        }
        rawOut[i] = rv;
        spOut[i] = sv;
        pb[i] = sv;
    }
}

extern "C" void kernel_launch(void* const* d_in, const int* in_sizes, int n_in,
                              void* d_out, int out_size, void* d_ws, size_t ws_size,
                              hipStream_t stream) {
    const float* images = (const float*)d_in[0];
    const float* wih    = (const float*)d_in[1];
    const float* whh    = (const float*)d_in[2];
    const float* bih    = (const float*)d_in[3];
    const float* bhh    = (const float*)d_in[4];
    float* out = (float*)d_out;
    float* ws  = (float*)d_ws;

    float* pose = ws;                       // 107584
    float* hA   = pose + 107584;            // 3442688
    float* hB   = hA + 3442688;             // 3442688
    float* cst  = hB + 3442688;             // 3442688
    float* regb = cst + 3442688;            // 3442688
    float* rawp = regb + 3442688;           // 93312 (2 x 16 x 4 x 27 x 27)
    float* Wc   = rawp + 93312;             // 131072
    float* bc   = Wc + 131072;              // 512

    hipMemsetAsync(hA, 0, (size_t)3442688 * 4, stream);
    hipMemsetAsync(cst, 0, (size_t)3442688 * 4, stream);
    k_init<<<421, 256, 0, stream>>>(pose);
    k_prep<<<512, 256, 0, stream>>>(wih, whh, bih, bhh, Wc, bc);

    float* hin = hA;
    float* hout = hB;
    for (int t = 0; t < NSTEP; ++t) {
        k_register<<<BB * EE, 256, 0, stream>>>(images, pose, regb, t);
        k_lstm<<<dim3((NROWS + 63) / 64, 8), 256, 0, stream>>>(regb, hin, Wc, bc, hout, cst);
        k_maps<<<dim3(53, 4, BB), 256, 0, stream>>>(hout, out, t);
        k_localize<<<dim3(4, OO, BB * 2), 256, 0, stream>>>(hout, images, rawp, t);
        k_softmax<<<BB, 256, 0, stream>>>(rawp, out, pose, t);
        float* tmp = hin; hin = hout; hout = tmp;
    }
}

// Round 4
// 8332.644 us; speedup vs baseline: 3.8750x; 1.7167x over previous
//
#include <hip/hip_runtime.h>
#include <math.h>

// Problem constants
#define BB 16      // batch
#define TT 16      // time (input)
#define EE 128     // embed
#define KS 15      // kernel
#define MM 41      // map size
#define OO 4       // orientations
#define VR 7       // view range
#define SS 27      // localize output spatial (41 - 2*7)
#define NSTEP 15
#define PP (MM*MM)          // 1681
#define NROWS (BB*PP)       // 26896

#define RAWS_OFF 0
#define SPS_OFF  1613760            // 16*15*4*1681
#define MAPS_OFF 3227520            // 2*SPS

#define PM 55               // padded map (41 + 2*7)
#define PMSZ (PM*PM)        // 3025

__device__ __forceinline__ float sigf(float x) { return 1.f / (1.f + expf(-x)); }

// rotate kernel coords (r,c) by o*90deg CCW -> source (ir,ic) in 15x15 image
__device__ __forceinline__ int rotoff(int o, int r, int c) {
    int ir, ic;
    if (o == 0)      { ir = r;      ic = c;      }
    else if (o == 1) { ir = c;      ic = 14 - r; }
    else if (o == 2) { ir = 14 - r; ic = 14 - c; }
    else             { ir = 14 - c; ic = r;      }
    return ir * 15 + ic;
}

// ---------------- pose init: zeros + one-hot at (o=0, 20,20) ----------------
__global__ void k_init(float* __restrict__ pose) {
    int idx = blockIdx.x * 256 + threadIdx.x;
    if (idx < BB * OO * MM * MM) {
        int r = idx % (OO * MM * MM);
        pose[idx] = (r == (20 * MM + 20)) ? 1.f : 0.f;
    }
}

// ---------------- weight prep: Wc[k][jp], jp = jj*4+g, j = g*128+jj ----------
__global__ void k_prep(const float* __restrict__ wih, const float* __restrict__ whh,
                       const float* __restrict__ bih, const float* __restrict__ bhh,
                       float* __restrict__ Wc, float* __restrict__ bc) {
    int idx = blockIdx.x * 256 + threadIdx.x;   // [0, 256*512)
    int k = idx >> 9, jp = idx & 511;
    int jj = jp >> 2, g = jp & 3, j = g * 128 + jj;
    Wc[idx] = (k < 128) ? wih[j * 128 + k] : whh[j * 128 + (k - 128)];
    if (idx < 512) {
        int jj2 = idx >> 2, g2 = idx & 3, j2 = g2 * 128 + jj2;
        bc[idx] = bih[j2] + bhh[j2];
    }
}

// ---------------- register: conv-transpose of pose with rotated images -------
// reg[b, p=(y,x), e] = sum_{o,dy,dx} pose[b,o,y+7-dy,x+7-dx] * rot_o(img[b,t])[e,dy,dx]
// Reformulated over IMG taps (R,C): weight read once, 4 inverse-rotated pose taps.
// Padded pose ps[r][c] = pose[r-7][c-7]; needed unpadded indices (per o):
//   o0: (y+7-R, x+7-C) -> padded (y+14-R, x+14-C)
//   o1: (y-7+C, x+7-R) -> padded (y+C,    x+14-R)
//   o2: (y-7+R, x-7+C) -> padded (y+R,    x+C)
//   o3: (y+7-C, x-7+R) -> padded (y+14-C, x+R)
// with pbase = (y+14)*PM + (x+14).
__global__ __launch_bounds__(256) void k_register(const float* __restrict__ images,
                                                  const float* __restrict__ pose,
                                                  float* __restrict__ reg, int t) {
    __shared__ float ps[OO * PMSZ];      // 48.4 KB padded pose
    __shared__ float wsm[225][36];       // 32.4 KB img quarter, transposed (+pad)
    const int p0 = blockIdx.x * 256;
    const int eq = blockIdx.y;           // e quarter: 32 e
    const int b  = blockIdx.z;
    const int tid = threadIdx.x;

    // stage padded pose (zeros in halo)
    for (int i = tid; i < OO * PMSZ; i += 256) {
        int o = i / PMSZ, rem = i % PMSZ, r = rem / PM, c = rem % PM;
        float v = 0.f;
        if (r >= VR && r < VR + MM && c >= VR && c < VR + MM)
            v = pose[(((size_t)b * OO + o) * MM + (r - VR)) * MM + (c - VR)];
        ps[i] = v;
    }
    // stage img quarter transposed: wsm[k][e] = img[e][k]
    const float* img = images + ((size_t)(b * TT + t) * EE + eq * 32) * 225;
    for (int i = tid; i < 32 * 225; i += 256) {
        int e = i / 225, k = i - e * 225;
        wsm[k][e] = img[e * 225 + k];
    }
    __syncthreads();

    const int px = tid & 63;
    const int ec = tid >> 6;             // 0..3, uniform per wave -> wsm broadcast
    int pbase[4];
    #pragma unroll
    for (int i = 0; i < 4; ++i) {
        int p = p0 + px + 64 * i;
        int pc = (p < PP) ? p : 0;
        int y = pc / MM, x = pc - y * MM;
        pbase[i] = (y + 2 * VR) * PM + (x + 2 * VR);   // FIX: padded coords (+2*VR, not +VR)
    }

    float acc[4][8];
    #pragma unroll
    for (int i = 0; i < 4; ++i)
        #pragma unroll
        for (int j = 0; j < 8; ++j) acc[i][j] = 0.f;

    for (int R = 0; R < 15; ++R) {
        #pragma unroll 5
        for (int C = 0; C < 15; ++C) {
            float4 wv0 = *(const float4*)&wsm[R * 15 + C][ec * 8];
            float4 wv1 = *(const float4*)&wsm[R * 15 + C][ec * 8 + 4];
            #pragma unroll
            for (int i = 0; i < 4; ++i) {
                float a0 = ps[0 * PMSZ + pbase[i] - R * PM - C];
                float a1 = ps[1 * PMSZ + pbase[i] + (C - 14) * PM - R];
                float a2 = ps[2 * PMSZ + pbase[i] + (R - 14) * PM + (C - 14)];
                float a3 = ps[3 * PMSZ + pbase[i] - C * PM + (R - 14)];
                acc[i][0] += a0 * wv0.x; acc[i][1] += a0 * wv0.y;
                acc[i][2] += a0 * wv0.z; acc[i][3] += a0 * wv0.w;
                acc[i][4] += a0 * wv1.x; acc[i][5] += a0 * wv1.y;
                acc[i][6] += a0 * wv1.z; acc[i][7] += a0 * wv1.w;
                acc[i][0] += a1 * wv0.x; acc[i][1] += a1 * wv0.y;
                acc[i][2] += a1 * wv0.z; acc[i][3] += a1 * wv0.w;
                acc[i][4] += a1 * wv1.x; acc[i][5] += a1 * wv1.y;
                acc[i][6] += a1 * wv1.z; acc[i][7] += a1 * wv1.w;
                acc[i][0] += a2 * wv0.x; acc[i][1] += a2 * wv0.y;
                acc[i][2] += a2 * wv0.z; acc[i][3] += a2 * wv0.w;
                acc[i][4] += a2 * wv1.x; acc[i][5] += a2 * wv1.y;
                acc[i][6] += a2 * wv1.z; acc[i][7] += a2 * wv1.w;
                acc[i][0] += a3 * wv0.x; acc[i][1] += a3 * wv0.y;
                acc[i][2] += a3 * wv0.z; acc[i][3] += a3 * wv0.w;
                acc[i][4] += a3 * wv1.x; acc[i][5] += a3 * wv1.y;
                acc[i][6] += a3 * wv1.z; acc[i][7] += a3 * wv1.w;
            }
        }
    }

    #pragma unroll
    for (int i = 0; i < 4; ++i) {
        int p = p0 + px + 64 * i;
        if (p < PP) {
            float* dst = reg + ((size_t)b * PP + p) * EE + eq * 32 + ec * 8;
            *(float4*)dst = make_float4(acc[i][0], acc[i][1], acc[i][2], acc[i][3]);
            *(float4*)(dst + 4) = make_float4(acc[i][4], acc[i][5], acc[i][6], acc[i][7]);
        }
    }
}

// ---------------- LSTM: gates GEMM [NROWS x 256]@[256 x 512] + epilogue ------
__global__ __launch_bounds__(256) void k_lstm(const float* __restrict__ regb,
                                              const float* __restrict__ hin,
                                              const float* __restrict__ Wc,
                                              const float* __restrict__ bc,
                                              float* __restrict__ hout,
                                              float* __restrict__ cst) {
    __shared__ float As[64][17];
    __shared__ __align__(16) float Wsm[16][64];
    const int tid = threadIdx.x;
    const int tx = tid & 15;     // col group (jj)
    const int ty = tid >> 4;     // row group
    const int n0 = blockIdx.x * 64;
    const int jp0 = blockIdx.y * 64;

    const int a_nl = tid >> 2;
    const int a_kl = (tid & 3) * 4;
    const int w_kl = tid >> 4;
    const int w_jl = (tid & 15) * 4;

    float acc[4][4] = {{0.f}};

    for (int kt = 0; kt < 16; ++kt) {
        const float* src = (kt < 8) ? regb : hin;
        const int koff = (kt < 8) ? kt * 16 : (kt - 8) * 16;
        int n = n0 + a_nl;
        float4 av = make_float4(0.f, 0.f, 0.f, 0.f);
        if (n < NROWS) av = *(const float4*)(src + (size_t)n * EE + koff + a_kl);
        As[a_nl][a_kl + 0] = av.x; As[a_nl][a_kl + 1] = av.y;
        As[a_nl][a_kl + 2] = av.z; As[a_nl][a_kl + 3] = av.w;
        float4 wv = *(const float4*)(Wc + (size_t)(kt * 16 + w_kl) * 512 + jp0 + w_jl);
        *(float4*)&Wsm[w_kl][w_jl] = wv;
        __syncthreads();
        #pragma unroll
        for (int kl = 0; kl < 16; ++kl) {
            float a0 = As[ty * 4 + 0][kl];
            float a1 = As[ty * 4 + 1][kl];
            float a2 = As[ty * 4 + 2][kl];
            float a3 = As[ty * 4 + 3][kl];
            float4 bv = *(const float4*)&Wsm[kl][tx * 4];
            acc[0][0] += a0 * bv.x; acc[0][1] += a0 * bv.y; acc[0][2] += a0 * bv.z; acc[0][3] += a0 * bv.w;
            acc[1][0] += a1 * bv.x; acc[1][1] += a1 * bv.y; acc[1][2] += a1 * bv.z; acc[1][3] += a1 * bv.w;
            acc[2][0] += a2 * bv.x; acc[2][1] += a2 * bv.y; acc[2][2] += a2 * bv.z; acc[2][3] += a2 * bv.w;
            acc[3][0] += a3 * bv.x; acc[3][1] += a3 * bv.y; acc[3][2] += a3 * bv.z; acc[3][3] += a3 * bv.w;
        }
        __syncthreads();
    }

    const int jj = (jp0 >> 2) + tx;
    float4 bv = *(const float4*)(bc + jj * 4);
    #pragma unroll
    for (int i = 0; i < 4; ++i) {
        int n = n0 + ty * 4 + i;
        if (n >= NROWS) continue;
        float gi = acc[i][0] + bv.x;
        float gf = acc[i][1] + bv.y;
        float gg = acc[i][2] + bv.z;
        float go = acc[i][3] + bv.w;
        size_t off = (size_t)n * EE + jj;
        float cv = cst[off];
        float c2 = sigf(gf) * cv + sigf(gi) * tanhf(gg);
        float h2 = sigf(go) * tanhf(c2);
        cst[off] = c2;
        hout[off] = h2;
    }
}

// ---------------- maps: transpose h[(b,p),e] -> out[b,t,e,p] -----------------
__global__ __launch_bounds__(256) void k_maps(const float* __restrict__ h,
                                              float* __restrict__ out, int t) {
    __shared__ float tile[32][33];
    const int b = blockIdx.z;
    const int p0 = blockIdx.x * 32;
    const int e0 = blockIdx.y * 32;
    const int tx = threadIdx.x & 31;
    const int ty0 = threadIdx.x >> 5;
    for (int ty = ty0; ty < 32; ty += 8) {
        int p = p0 + ty;
        tile[ty][tx] = (p < PP) ? h[((size_t)b * PP + p) * EE + e0 + tx] : 0.f;
    }
    __syncthreads();
    size_t base = MAPS_OFF + ((size_t)(b * NSTEP + t) * EE) * PP;
    for (int ty = ty0; ty < 32; ty += 8) {
        int e = e0 + ty;
        int p = p0 + tx;
        if (p < PP) out[base + (size_t)e * PP + p] = tile[tx][ty];
    }
}

// ---------------- localize: raw[b,o,y,x] = sum_{e,dy,dx} m*w -----------------
// LDS-staged rotated weights (e-half per block), register-cached weight
// fragments reused across a 7-row accumulator strip.
// rawp layout: [eh=2][b][o][27][27] partial sums; softmax adds the halves.
__global__ __launch_bounds__(256) void k_localize(const float* __restrict__ h,
                                                  const float* __restrict__ images,
                                                  float* __restrict__ rawp, int t) {
    __shared__ float wsm[225][64];     // 57.6 KB
    const int y0 = blockIdx.x * 7;     // ytile: 0,7,14,21
    const int o  = blockIdx.y;
    const int b  = blockIdx.z >> 1;
    const int eh = blockIdx.z & 1;
    const int tid = threadIdx.x;

    // stage rotated weights: wsm[k][e] = img[e][rotoff(o, k/15, k%15)]
    const float* img = images + ((size_t)(b * TT + t + 1) * EE + eh * 64) * 225;
    for (int i = tid; i < 225 * 64; i += 256) {
        int k = i >> 6, e = i & 63;
        int r = k / 15, c = k - r * 15;
        wsm[k][e] = img[e * 225 + rotoff(o, r, c)];
    }
    __syncthreads();

    const int ec = tid & 7;            // 8 e's per lane group
    const int xc = tid >> 3;           // 0..31, active 0..26
    float acc[7] = {0.f, 0.f, 0.f, 0.f, 0.f, 0.f, 0.f};

    if (xc < SS) {
        const float* hb = h + (size_t)b * PP * EE + eh * 64 + ec * 8;
        int dy = 0, dx = 0;
        for (int k = 0; k < 225; ++k) {
            float4 w0 = *(const float4*)&wsm[k][ec * 8];
            float4 w1 = *(const float4*)&wsm[k][ec * 8 + 4];
            const float* hp = hb + (size_t)((y0 + dy) * MM + xc + dx) * EE;
            #pragma unroll
            for (int yy = 0; yy < 7; ++yy) {
                if (y0 + yy < SS) {
                    float4 h0 = *(const float4*)(hp + yy * (MM * EE));
                    float4 h1 = *(const float4*)(hp + yy * (MM * EE) + 4);
                    acc[yy] += h0.x * w0.x + h0.y * w0.y + h0.z * w0.z + h0.w * w0.w
                             + h1.x * w1.x + h1.y * w1.y + h1.z * w1.z + h1.w * w1.w;
                }
            }
            if (++dx == 15) { dx = 0; ++dy; }
        }
    }

    // reduce across the 8 ec lanes (consecutive lanes within a wave)
    #pragma unroll
    for (int yy = 0; yy < 7; ++yy) {
        float v = acc[yy];
        v += __shfl_xor(v, 1);
        v += __shfl_xor(v, 2);
        v += __shfl_xor(v, 4);
        if (ec == 0 && xc < SS && y0 + yy < SS) {
            rawp[(((size_t)eh * BB + b) * OO + o) * (SS * SS) + (y0 + yy) * SS + xc] = v;
        }
    }
}

// ---------------- softmax over (O*27*27) + padded writes + pose update -------
__global__ __launch_bounds__(256) void k_softmax(const float* __restrict__ rawp,
                                                 float* __restrict__ out,
                                                 float* __restrict__ pose, int t) {
    const int b = blockIdx.x, tid = threadIdx.x;
    __shared__ float red[256];
    const float* r0 = rawp + (size_t)b * (OO * SS * SS);
    const float* r1 = rawp + (size_t)(BB + b) * (OO * SS * SS);
    const int NTOT = OO * SS * SS;  // 2916

    float mx = -3.4e38f;
    for (int i = tid; i < NTOT; i += 256) mx = fmaxf(mx, r0[i] + r1[i]);
    red[tid] = mx; __syncthreads();
    for (int s = 128; s > 0; s >>= 1) {
        if (tid < s) red[tid] = fmaxf(red[tid], red[tid + s]);
        __syncthreads();
    }
    mx = red[0]; __syncthreads();

    float sm = 0.f;
    for (int i = tid; i < NTOT; i += 256) sm += expf(r0[i] + r1[i] - mx);
    red[tid] = sm; __syncthreads();
    for (int s = 128; s > 0; s >>= 1) {
        if (tid < s) red[tid] += red[tid + s];
        __syncthreads();
    }
    const float inv = 1.f / red[0];

    float* rawOut = out + RAWS_OFF + ((size_t)(b * NSTEP + t) * OO) * PP;
    float* spOut  = out + SPS_OFF  + ((size_t)(b * NSTEP + t) * OO) * PP;
    float* pb = pose + (size_t)b * OO * MM * MM;
    for (int i = tid; i < OO * MM * MM; i += 256) {
        int o = i / (MM * MM), rem = i % (MM * MM), yy = rem / MM - VR, xx = rem % MM - VR;
        float rv = 0.f, sv = 0.f;
        if ((unsigned)yy < SS && (unsigned)xx < SS) {
            int idx = (o * SS + yy) * SS + xx;
            float r = r0[idx] + r1[idx];
            rv = r;
            sv = expf(r - mx) * inv;
        }
        rawOut[i] = rv;
        spOut[i] = sv;
        pb[i] = sv;
    }
}

extern "C" void kernel_launch(void* const* d_in, const int* in_sizes, int n_in,
                              void* d_out, int out_size, void* d_ws, size_t ws_size,
                              hipStream_t stream) {
    const float* images = (const float*)d_in[0];
    const float* wih    = (const float*)d_in[1];
    const float* whh    = (const float*)d_in[2];
    const float* bih    = (const float*)d_in[3];
    const float* bhh    = (const float*)d_in[4];
    float* out = (float*)d_out;
    float* ws  = (float*)d_ws;

    float* pose = ws;                       // 107584
    float* hA   = pose + 107584;            // 3442688
    float* hB   = hA + 3442688;             // 3442688
    float* cst  = hB + 3442688;             // 3442688
    float* regb = cst + 3442688;            // 3442688
    float* rawp = regb + 3442688;           // 93312 (2 x 16 x 4 x 27 x 27)
    float* Wc   = rawp + 93312;             // 131072
    float* bc   = Wc + 131072;              // 512

    hipMemsetAsync(hA, 0, (size_t)3442688 * 4, stream);
    hipMemsetAsync(cst, 0, (size_t)3442688 * 4, stream);
    k_init<<<421, 256, 0, stream>>>(pose);
    k_prep<<<512, 256, 0, stream>>>(wih, whh, bih, bhh, Wc, bc);

    float* hin = hA;
    float* hout = hB;
    for (int t = 0; t < NSTEP; ++t) {
        k_register<<<dim3(7, 4, BB), 256, 0, stream>>>(images, pose, regb, t);
        k_lstm<<<dim3((NROWS + 63) / 64, 8), 256, 0, stream>>>(regb, hin, Wc, bc, hout, cst);
        k_maps<<<dim3(53, 4, BB), 256, 0, stream>>>(hout, out, t);
        k_localize<<<dim3(4, OO, BB * 2), 256, 0, stream>>>(hout, images, rawp, t);
        k_softmax<<<BB, 256, 0, stream>>>(rawp, out, pose, t);
        float* tmp = hin; hin = hout; hout = tmp;
    }
}

// Round 5
// 7183.350 us; speedup vs baseline: 4.4950x; 1.1600x over previous
//
#include <hip/hip_runtime.h>
#include <math.h>

// Problem constants
#define BB 16      // batch
#define TT 16      // time (input)
#define EE 128     // embed
#define KS 15      // kernel
#define MM 41      // map size
#define OO 4       // orientations
#define VR 7       // view range
#define SS 27      // localize output spatial (41 - 2*7)
#define NSTEP 15
#define PP (MM*MM)          // 1681
#define NROWS (BB*PP)       // 26896

#define RAWS_OFF 0
#define SPS_OFF  1613760            // 16*15*4*1681
#define MAPS_OFF 3227520            // 2*SPS

#define PM 55               // padded map (41 + 2*7)
#define PMSZ (PM*PM)        // 3025

__device__ __forceinline__ float sigf(float x) { return 1.f / (1.f + expf(-x)); }

// rotate kernel coords (r,c) by o*90deg CCW -> source (ir,ic) in 15x15 image
__device__ __forceinline__ int rotoff(int o, int r, int c) {
    int ir, ic;
    if (o == 0)      { ir = r;      ic = c;      }
    else if (o == 1) { ir = c;      ic = 14 - r; }
    else if (o == 2) { ir = 14 - r; ic = 14 - c; }
    else             { ir = 14 - c; ic = r;      }
    return ir * 15 + ic;
}

// ---------------- pose init: zeros + one-hot at (o=0, 20,20) ----------------
__global__ void k_init(float* __restrict__ pose) {
    int idx = blockIdx.x * 256 + threadIdx.x;
    if (idx < BB * OO * MM * MM) {
        int r = idx % (OO * MM * MM);
        pose[idx] = (r == (20 * MM + 20)) ? 1.f : 0.f;
    }
}

// ---------------- weight prep: Wc[k][jp], jp = jj*4+g, j = g*128+jj ----------
__global__ void k_prep(const float* __restrict__ wih, const float* __restrict__ whh,
                       const float* __restrict__ bih, const float* __restrict__ bhh,
                       float* __restrict__ Wc, float* __restrict__ bc) {
    int idx = blockIdx.x * 256 + threadIdx.x;   // [0, 256*512)
    int k = idx >> 9, jp = idx & 511;
    int jj = jp >> 2, g = jp & 3, j = g * 128 + jj;
    Wc[idx] = (k < 128) ? wih[j * 128 + k] : whh[j * 128 + (k - 128)];
    if (idx < 512) {
        int jj2 = idx >> 2, g2 = idx & 3, j2 = g2 * 128 + jj2;
        bc[idx] = bih[j2] + bhh[j2];
    }
}

// ---------------- register: conv-transpose of pose with rotated images -------
// reg[b, p=(y,x), e] = sum_{o,dy,dx} pose[b,o,y+7-dy,x+7-dx] * rot_o(img[b,t])[e,dy,dx]
// Reformulated over IMG taps (R,C): weight read once, 4 inverse-rotated pose taps.
// Padded pose ps[r][c] = pose[r-7][c-7]; pbase = (y+14)*PM + (x+14).
__global__ __launch_bounds__(256) void k_register(const float* __restrict__ images,
                                                  const float* __restrict__ pose,
                                                  float* __restrict__ reg, int t) {
    __shared__ float ps[OO * PMSZ];      // 48.4 KB padded pose
    __shared__ float wsm[225][36];       // 32.4 KB img quarter, transposed (+pad)
    const int p0 = blockIdx.x * 256;
    const int eq = blockIdx.y;           // e quarter: 32 e
    const int b  = blockIdx.z;
    const int tid = threadIdx.x;

    // stage padded pose (zeros in halo)
    for (int i = tid; i < OO * PMSZ; i += 256) {
        int o = i / PMSZ, rem = i % PMSZ, r = rem / PM, c = rem % PM;
        float v = 0.f;
        if (r >= VR && r < VR + MM && c >= VR && c < VR + MM)
            v = pose[(((size_t)b * OO + o) * MM + (r - VR)) * MM + (c - VR)];
        ps[i] = v;
    }
    // stage img quarter transposed: wsm[k][e] = img[e][k]
    const float* img = images + ((size_t)(b * TT + t) * EE + eq * 32) * 225;
    for (int i = tid; i < 32 * 225; i += 256) {
        int e = i / 225, k = i - e * 225;
        wsm[k][e] = img[e * 225 + k];
    }
    __syncthreads();

    const int px = tid & 63;
    const int ec = tid >> 6;             // 0..3, uniform per wave -> wsm broadcast
    int pbase[4];
    #pragma unroll
    for (int i = 0; i < 4; ++i) {
        int p = p0 + px + 64 * i;
        int pc = (p < PP) ? p : 0;
        int y = pc / MM, x = pc - y * MM;
        pbase[i] = (y + 2 * VR) * PM + (x + 2 * VR);
    }

    float acc[4][8];
    #pragma unroll
    for (int i = 0; i < 4; ++i)
        #pragma unroll
        for (int j = 0; j < 8; ++j) acc[i][j] = 0.f;

    for (int R = 0; R < 15; ++R) {
        #pragma unroll 5
        for (int C = 0; C < 15; ++C) {
            float4 wv0 = *(const float4*)&wsm[R * 15 + C][ec * 8];
            float4 wv1 = *(const float4*)&wsm[R * 15 + C][ec * 8 + 4];
            #pragma unroll
            for (int i = 0; i < 4; ++i) {
                float a0 = ps[0 * PMSZ + pbase[i] - R * PM - C];
                float a1 = ps[1 * PMSZ + pbase[i] + (C - 14) * PM - R];
                float a2 = ps[2 * PMSZ + pbase[i] + (R - 14) * PM + (C - 14)];
                float a3 = ps[3 * PMSZ + pbase[i] - C * PM + (R - 14)];
                acc[i][0] += a0 * wv0.x; acc[i][1] += a0 * wv0.y;
                acc[i][2] += a0 * wv0.z; acc[i][3] += a0 * wv0.w;
                acc[i][4] += a0 * wv1.x; acc[i][5] += a0 * wv1.y;
                acc[i][6] += a0 * wv1.z; acc[i][7] += a0 * wv1.w;
                acc[i][0] += a1 * wv0.x; acc[i][1] += a1 * wv0.y;
                acc[i][2] += a1 * wv0.z; acc[i][3] += a1 * wv0.w;
                acc[i][4] += a1 * wv1.x; acc[i][5] += a1 * wv1.y;
                acc[i][6] += a1 * wv1.z; acc[i][7] += a1 * wv1.w;
                acc[i][0] += a2 * wv0.x; acc[i][1] += a2 * wv0.y;
                acc[i][2] += a2 * wv0.z; acc[i][3] += a2 * wv0.w;
                acc[i][4] += a2 * wv1.x; acc[i][5] += a2 * wv1.y;
                acc[i][6] += a2 * wv1.z; acc[i][7] += a2 * wv1.w;
                acc[i][0] += a3 * wv0.x; acc[i][1] += a3 * wv0.y;
                acc[i][2] += a3 * wv0.z; acc[i][3] += a3 * wv0.w;
                acc[i][4] += a3 * wv1.x; acc[i][5] += a3 * wv1.y;
                acc[i][6] += a3 * wv1.z; acc[i][7] += a3 * wv1.w;
            }
        }
    }

    #pragma unroll
    for (int i = 0; i < 4; ++i) {
        int p = p0 + px + 64 * i;
        if (p < PP) {
            float* dst = reg + ((size_t)b * PP + p) * EE + eq * 32 + ec * 8;
            *(float4*)dst = make_float4(acc[i][0], acc[i][1], acc[i][2], acc[i][3]);
            *(float4*)(dst + 4) = make_float4(acc[i][4], acc[i][5], acc[i][6], acc[i][7]);
        }
    }
}

// ---------------- LSTM: gates GEMM [NROWS x 256]@[256 x 512] + epilogue ------
__global__ __launch_bounds__(256) void k_lstm(const float* __restrict__ regb,
                                              const float* __restrict__ hin,
                                              const float* __restrict__ Wc,
                                              const float* __restrict__ bc,
                                              float* __restrict__ hout,
                                              float* __restrict__ cst) {
    __shared__ float As[64][17];
    __shared__ __align__(16) float Wsm[16][64];
    const int tid = threadIdx.x;
    const int tx = tid & 15;     // col group (jj)
    const int ty = tid >> 4;     // row group
    const int n0 = blockIdx.x * 64;
    const int jp0 = blockIdx.y * 64;

    const int a_nl = tid >> 2;
    const int a_kl = (tid & 3) * 4;
    const int w_kl = tid >> 4;
    const int w_jl = (tid & 15) * 4;

    float acc[4][4] = {{0.f}};

    for (int kt = 0; kt < 16; ++kt) {
        const float* src = (kt < 8) ? regb : hin;
        const int koff = (kt < 8) ? kt * 16 : (kt - 8) * 16;
        int n = n0 + a_nl;
        float4 av = make_float4(0.f, 0.f, 0.f, 0.f);
        if (n < NROWS) av = *(const float4*)(src + (size_t)n * EE + koff + a_kl);
        As[a_nl][a_kl + 0] = av.x; As[a_nl][a_kl + 1] = av.y;
        As[a_nl][a_kl + 2] = av.z; As[a_nl][a_kl + 3] = av.w;
        float4 wv = *(const float4*)(Wc + (size_t)(kt * 16 + w_kl) * 512 + jp0 + w_jl);
        *(float4*)&Wsm[w_kl][w_jl] = wv;
        __syncthreads();
        #pragma unroll
        for (int kl = 0; kl < 16; ++kl) {
            float a0 = As[ty * 4 + 0][kl];
            float a1 = As[ty * 4 + 1][kl];
            float a2 = As[ty * 4 + 2][kl];
            float a3 = As[ty * 4 + 3][kl];
            float4 bv = *(const float4*)&Wsm[kl][tx * 4];
            acc[0][0] += a0 * bv.x; acc[0][1] += a0 * bv.y; acc[0][2] += a0 * bv.z; acc[0][3] += a0 * bv.w;
            acc[1][0] += a1 * bv.x; acc[1][1] += a1 * bv.y; acc[1][2] += a1 * bv.z; acc[1][3] += a1 * bv.w;
            acc[2][0] += a2 * bv.x; acc[2][1] += a2 * bv.y; acc[2][2] += a2 * bv.z; acc[2][3] += a2 * bv.w;
            acc[3][0] += a3 * bv.x; acc[3][1] += a3 * bv.y; acc[3][2] += a3 * bv.z; acc[3][3] += a3 * bv.w;
        }
        __syncthreads();
    }

    const int jj = (jp0 >> 2) + tx;
    float4 bv = *(const float4*)(bc + jj * 4);
    #pragma unroll
    for (int i = 0; i < 4; ++i) {
        int n = n0 + ty * 4 + i;
        if (n >= NROWS) continue;
        float gi = acc[i][0] + bv.x;
        float gf = acc[i][1] + bv.y;
        float gg = acc[i][2] + bv.z;
        float go = acc[i][3] + bv.w;
        size_t off = (size_t)n * EE + jj;
        float cv = cst[off];
        float c2 = sigf(gf) * cv + sigf(gi) * tanhf(gg);
        float h2 = sigf(go) * tanhf(c2);
        cst[off] = c2;
        hout[off] = h2;
    }
}

// ---------------- maps: transpose h[(b,p),e] -> out[b,t,e,p] -----------------
__global__ __launch_bounds__(256) void k_maps(const float* __restrict__ h,
                                              float* __restrict__ out, int t) {
    __shared__ float tile[32][33];
    const int b = blockIdx.z;
    const int p0 = blockIdx.x * 32;
    const int e0 = blockIdx.y * 32;
    const int tx = threadIdx.x & 31;
    const int ty0 = threadIdx.x >> 5;
    for (int ty = ty0; ty < 32; ty += 8) {
        int p = p0 + ty;
        tile[ty][tx] = (p < PP) ? h[((size_t)b * PP + p) * EE + e0 + tx] : 0.f;
    }
    __syncthreads();
    size_t base = MAPS_OFF + ((size_t)(b * NSTEP + t) * EE) * PP;
    for (int ty = ty0; ty < 32; ty += 8) {
        int e = e0 + ty;
        int p = p0 + tx;
        if (p < PP) out[base + (size_t)e * PP + p] = tile[tx][ty];
    }
}

// ---------------- localize: raw[b,o,y,x] = sum_{e,dy,dx} m*w -----------------
// e split into QUARTERS (32 e) per block: LDS 28.8 KB -> 5 blocks/CU (was 2).
// Thread map: ec = tid&3 (4 groups of 8e), x = (tid>>2)&31, ys = tid>>7 (y substrip).
// rawp layout: [eq=4][b][o][27][27] partial sums; softmax adds the quarters.
__global__ __launch_bounds__(256) void k_localize(const float* __restrict__ h,
                                                  const float* __restrict__ images,
                                                  float* __restrict__ rawp, int t) {
    __shared__ float wsm[225][32];     // 28.8 KB
    const int y0 = blockIdx.x * 7;     // ytile: 0,7,14,21
    const int o  = blockIdx.y;
    const int b  = blockIdx.z >> 2;
    const int eq = blockIdx.z & 3;
    const int tid = threadIdx.x;

    // stage rotated weights: wsm[k][e] = img[e][rotoff(o, k/15, k%15)]
    const float* img = images + ((size_t)(b * TT + t + 1) * EE + eq * 32) * 225;
    for (int i = tid; i < 225 * 32; i += 256) {
        int k = i >> 5, e = i & 31;
        int r = k / 15, c = k - r * 15;
        wsm[k][e] = img[e * 225 + rotoff(o, r, c)];
    }
    __syncthreads();

    const int ec = tid & 3;            // 4 e-groups of 8
    const int x  = (tid >> 2) & 31;    // 0..31, active 0..26
    const int ys = tid >> 7;           // 0/1 (uniform per wave)
    const int ybase = ys * 4;          // yy = ybase..ybase+3 (ys=1: 3 rows)
    const int nyy = ys ? 3 : 4;
    float acc[4] = {0.f, 0.f, 0.f, 0.f};

    if (x < SS) {
        const float* hb = h + (size_t)b * PP * EE + eq * 32 + ec * 8;
        int dy = 0, dx = 0;
        for (int k = 0; k < 225; ++k) {
            float4 w0 = *(const float4*)&wsm[k][ec * 8];
            float4 w1 = *(const float4*)&wsm[k][ec * 8 + 4];
            const float* hp = hb + (size_t)((y0 + ybase + dy) * MM + x + dx) * EE;
            #pragma unroll
            for (int q = 0; q < 4; ++q) {
                if (q < nyy && y0 + ybase + q < SS) {
                    float4 h0 = *(const float4*)(hp + q * (MM * EE));
                    float4 h1 = *(const float4*)(hp + q * (MM * EE) + 4);
                    acc[q] += h0.x * w0.x + h0.y * w0.y + h0.z * w0.z + h0.w * w0.w
                            + h1.x * w1.x + h1.y * w1.y + h1.z * w1.z + h1.w * w1.w;
                }
            }
            if (++dx == 15) { dx = 0; ++dy; }
        }
    }

    // reduce across the 4 ec lanes (consecutive lanes within a wave)
    #pragma unroll
    for (int q = 0; q < 4; ++q) {
        float v = acc[q];
        v += __shfl_xor(v, 1);
        v += __shfl_xor(v, 2);
        int yy = ybase + q;
        if (ec == 0 && x < SS && q < nyy && y0 + yy < SS) {
            rawp[(((size_t)eq * BB + b) * OO + o) * (SS * SS) + (y0 + yy) * SS + x] = v;
        }
    }
}

// ---------------- softmax over (O*27*27) + padded writes + pose update -------
__global__ __launch_bounds__(256) void k_softmax(const float* __restrict__ rawp,
                                                 float* __restrict__ out,
                                                 float* __restrict__ pose, int t) {
    const int b = blockIdx.x, tid = threadIdx.x;
    __shared__ float red[256];
    const float* r0 = rawp + (size_t)(0 * BB + b) * (OO * SS * SS);
    const float* r1 = rawp + (size_t)(1 * BB + b) * (OO * SS * SS);
    const float* r2 = rawp + (size_t)(2 * BB + b) * (OO * SS * SS);
    const float* r3 = rawp + (size_t)(3 * BB + b) * (OO * SS * SS);
    const int NTOT = OO * SS * SS;  // 2916

    float mx = -3.4e38f;
    for (int i = tid; i < NTOT; i += 256) mx = fmaxf(mx, (r0[i] + r1[i]) + (r2[i] + r3[i]));
    red[tid] = mx; __syncthreads();
    for (int s = 128; s > 0; s >>= 1) {
        if (tid < s) red[tid] = fmaxf(red[tid], red[tid + s]);
        __syncthreads();
    }
    mx = red[0]; __syncthreads();

    float sm = 0.f;
    for (int i = tid; i < NTOT; i += 256) sm += expf((r0[i] + r1[i]) + (r2[i] + r3[i]) - mx);
    red[tid] = sm; __syncthreads();
    for (int s = 128; s > 0; s >>= 1) {
        if (tid < s) red[tid] += red[tid + s];
        __syncthreads();
    }
    const float inv = 1.f / red[0];

    float* rawOut = out + RAWS_OFF + ((size_t)(b * NSTEP + t) * OO) * PP;
    float* spOut  = out + SPS_OFF  + ((size_t)(b * NSTEP + t) * OO) * PP;
    float* pb = pose + (size_t)b * OO * MM * MM;
    for (int i = tid; i < OO * MM * MM; i += 256) {
        int o = i / (MM * MM), rem = i % (MM * MM), yy = rem / MM - VR, xx = rem % MM - VR;
        float rv = 0.f, sv = 0.f;
        if ((unsigned)yy < SS && (unsigned)xx < SS) {
            int idx = (o * SS + yy) * SS + xx;
            float r = (r0[idx] + r1[idx]) + (r2[idx] + r3[idx]);
            rv = r;
            sv = expf(r - mx) * inv;
        }
        rawOut[i] = rv;
        spOut[i] = sv;
        pb[i] = sv;
    }
}

extern "C" void kernel_launch(void* const* d_in, const int* in_sizes, int n_in,
                              void* d_out, int out_size, void* d_ws, size_t ws_size,
                              hipStream_t stream) {
    const float* images = (const float*)d_in[0];
    const float* wih    = (const float*)d_in[1];
    const float* whh    = (const float*)d_in[2];
    const float* bih    = (const float*)d_in[3];
    const float* bhh    = (const float*)d_in[4];
    float* out = (float*)d_out;
    float* ws  = (float*)d_ws;

    float* pose = ws;                       // 107584
    float* hA   = pose + 107584;            // 3442688
    float* hB   = hA + 3442688;             // 3442688
    float* cst  = hB + 3442688;             // 3442688
    float* regb = cst + 3442688;            // 3442688
    float* rawp = regb + 3442688;           // 186624 (4 x 16 x 4 x 27 x 27)
    float* Wc   = rawp + 186624;            // 131072
    float* bc   = Wc + 131072;              // 512

    hipMemsetAsync(hA, 0, (size_t)3442688 * 4, stream);
    hipMemsetAsync(cst, 0, (size_t)3442688 * 4, stream);
    k_init<<<421, 256, 0, stream>>>(pose);
    k_prep<<<512, 256, 0, stream>>>(wih, whh, bih, bhh, Wc, bc);

    float* hin = hA;
    float* hout = hB;
    for (int t = 0; t < NSTEP; ++t) {
        k_register<<<dim3(7, 4, BB), 256, 0, stream>>>(images, pose, regb, t);
        k_lstm<<<dim3((NROWS + 63) / 64, 8), 256, 0, stream>>>(regb, hin, Wc, bc, hout, cst);
        k_maps<<<dim3(53, 4, BB), 256, 0, stream>>>(hout, out, t);
        k_localize<<<dim3(4, OO, BB * 4), 256, 0, stream>>>(hout, images, rawp, t);
        k_softmax<<<BB, 256, 0, stream>>>(rawp, out, pose, t);
        float* tmp = hin; hin = hout; hout = tmp;
    }
}